// Round 5
// baseline (86.912 us; speedup 1.0000x reference)
//
#include <hip/hip_runtime.h>
#include <hip/hip_fp16.h>

// KirchhoffNet: out[n] = sum_{dst==n} cur - sum_{src==n} cur,
// cur = cond * relu(t1*(v[src]-v[dst]) + t2)
//
// Round 5: 3-pass, no global atomics.
//  P0: per-edge current -> f16 cur[] (8 edges/thread for 16 gathers in flight)
//  P1: node-range LDS accumulation, RANGE=32K (128 KiB LDS, 1 block/CU),
//      R=4 passes over edges, LDS atomics only, dense flush (no memset needed)
//  P2: reduce B partial copies.

#define RANGE   32768
#define P1_BLK  1024
#define P0_BLK  256

__global__ __launch_bounds__(P0_BLK) void edge_current_kernel(
    const float* __restrict__ v,
    const int*   __restrict__ src,
    const int*   __restrict__ dst,
    const float* __restrict__ t1,
    const float* __restrict__ t2,
    const float* __restrict__ cond,
    __half*      __restrict__ cur,
    int E)
{
    const int E8 = E & ~7;
    const int tid = blockIdx.x * blockDim.x + threadIdx.x;
    const int nthreads = gridDim.x * blockDim.x;

    for (int i = tid * 8; i < E8; i += nthreads * 8) {
        int4   sa = *(const int4*)  (src  + i);
        int4   sb = *(const int4*)  (src  + i + 4);
        int4   da = *(const int4*)  (dst  + i);
        int4   db = *(const int4*)  (dst  + i + 4);
        float4 aa = *(const float4*)(t1   + i);
        float4 ab = *(const float4*)(t1   + i + 4);
        float4 ba = *(const float4*)(t2   + i);
        float4 bb = *(const float4*)(t2   + i + 4);
        float4 ca = *(const float4*)(cond + i);
        float4 cb = *(const float4*)(cond + i + 4);

        // issue all 16 gathers before consuming any
        float vs0 = v[sa.x], vs1 = v[sa.y], vs2 = v[sa.z], vs3 = v[sa.w];
        float vs4 = v[sb.x], vs5 = v[sb.y], vs6 = v[sb.z], vs7 = v[sb.w];
        float vd0 = v[da.x], vd1 = v[da.y], vd2 = v[da.z], vd3 = v[da.w];
        float vd4 = v[db.x], vd5 = v[db.y], vd6 = v[db.z], vd7 = v[db.w];

        float x0 = fmaf(aa.x, vs0 - vd0, ba.x);
        float x1 = fmaf(aa.y, vs1 - vd1, ba.y);
        float x2 = fmaf(aa.z, vs2 - vd2, ba.z);
        float x3 = fmaf(aa.w, vs3 - vd3, ba.w);
        float x4 = fmaf(ab.x, vs4 - vd4, bb.x);
        float x5 = fmaf(ab.y, vs5 - vd5, bb.y);
        float x6 = fmaf(ab.z, vs6 - vd6, bb.z);
        float x7 = fmaf(ab.w, vs7 - vd7, bb.w);

        float c0 = x0 > 0.0f ? ca.x * x0 : 0.0f;
        float c1 = x1 > 0.0f ? ca.y * x1 : 0.0f;
        float c2 = x2 > 0.0f ? ca.z * x2 : 0.0f;
        float c3 = x3 > 0.0f ? ca.w * x3 : 0.0f;
        float c4 = x4 > 0.0f ? cb.x * x4 : 0.0f;
        float c5 = x5 > 0.0f ? cb.y * x5 : 0.0f;
        float c6 = x6 > 0.0f ? cb.z * x6 : 0.0f;
        float c7 = x7 > 0.0f ? cb.w * x7 : 0.0f;

        union { __half2 h[4]; float4 f; } u;
        u.h[0] = __floats2half2_rn(c0, c1);
        u.h[1] = __floats2half2_rn(c2, c3);
        u.h[2] = __floats2half2_rn(c4, c5);
        u.h[3] = __floats2half2_rn(c6, c7);
        *(float4*)(cur + i) = u.f;
    }

    for (int t = E8 + tid; t < E; t += nthreads) {
        float x = fmaf(t1[t], v[src[t]] - v[dst[t]], t2[t]);
        cur[t] = __float2half(x > 0.0f ? cond[t] * x : 0.0f);
    }
}

__global__ __launch_bounds__(P1_BLK) void range_accum_kernel(
    const int*    __restrict__ src,
    const int*    __restrict__ dst,
    const __half* __restrict__ cur,
    float*        __restrict__ partial,   // [B][N]
    int N, int E, int B, int R, int sliceLen)
{
    __shared__ __align__(16) float acc[RANGE];   // 128 KiB

    const int r    = blockIdx.x % R;   // consecutive bids share slice b
    const int b    = blockIdx.x / R;
    const int base = r * RANGE;
    const int len  = min(RANGE, N - base);

    for (int i = threadIdx.x; i < RANGE; i += P1_BLK) acc[i] = 0.0f;
    __syncthreads();

    const int E4 = E & ~3;
    const int s0 = b * sliceLen;
    const int s1 = min(s0 + sliceLen, E4);

    #define PROC(S, D, C)                                          \
        if ((C) != 0.0f) {                                         \
            unsigned du = (unsigned)((D) - base);                  \
            if (du < (unsigned)len) atomicAdd(&acc[du],  (C));     \
            unsigned su = (unsigned)((S) - base);                  \
            if (su < (unsigned)len) atomicAdd(&acc[su], -(C));     \
        }

    for (int i = s0 + (int)threadIdx.x * 4; i < s1; i += P1_BLK * 4) {
        int4    ss = *(const int4*)   (src + i);
        int4    dd = *(const int4*)   (dst + i);
        ushort4 hh = *(const ushort4*)(cur + i);
        float c0 = __half2float(__ushort_as_half(hh.x));
        float c1 = __half2float(__ushort_as_half(hh.y));
        float c2 = __half2float(__ushort_as_half(hh.z));
        float c3 = __half2float(__ushort_as_half(hh.w));
        PROC(ss.x, dd.x, c0)
        PROC(ss.y, dd.y, c1)
        PROC(ss.z, dd.z, c2)
        PROC(ss.w, dd.w, c3)
    }
    // tail edges: every range must see them; handled by slice b==B-1
    if (b == B - 1) {
        for (int i = E4 + (int)threadIdx.x; i < E; i += P1_BLK) {
            float c = __half2float(cur[i]);
            PROC(src[i], dst[i], c)
        }
    }
    #undef PROC

    __syncthreads();
    // dense flush, fully overwrites partial[b][base..base+len) -> no memset
    float* outp = partial + (size_t)b * N + base;
    const int len4 = len & ~3;
    for (int i = (int)threadIdx.x * 4; i < len4; i += P1_BLK * 4)
        *(float4*)(outp + i) = *(const float4*)&acc[i];
    for (int i = len4 + (int)threadIdx.x; i < len; i += P1_BLK)
        outp[i] = acc[i];
}

__global__ __launch_bounds__(256) void reduce_kernel(
    const float* __restrict__ partial, float* __restrict__ out, int N4, int B)
{
    int n = blockIdx.x * blockDim.x + threadIdx.x;
    if (n < N4) {
        float4 s = make_float4(0.f, 0.f, 0.f, 0.f);
        for (int p = 0; p < B; ++p) {
            float4 q = ((const float4*)partial)[(size_t)p * N4 + n];
            s.x += q.x; s.y += q.y; s.z += q.z; s.w += q.w;
        }
        ((float4*)out)[n] = s;
    }
}

__global__ __launch_bounds__(256) void reduce_scalar_kernel(
    const float* __restrict__ partial, float* __restrict__ out, int N, int B)
{
    int n = blockIdx.x * blockDim.x + threadIdx.x;
    if (n < N) {
        float s = 0.0f;
        for (int p = 0; p < B; ++p) s += partial[(size_t)p * N + n];
        out[n] = s;
    }
}

// fallback if ws is too small: direct global atomics (slow but correct)
__global__ __launch_bounds__(256) void atomic_fallback_kernel(
    const float* __restrict__ v, const int* __restrict__ src, const int* __restrict__ dst,
    const float* __restrict__ t1, const float* __restrict__ t2, const float* __restrict__ cond,
    float* __restrict__ out, int E)
{
    int i = blockIdx.x * blockDim.x + threadIdx.x;
    int stride = gridDim.x * blockDim.x;
    for (; i < E; i += stride) {
        int s = src[i], d = dst[i];
        float x = fmaf(t1[i], v[s] - v[d], t2[i]);
        if (x > 0.0f) {
            float c = cond[i] * x;
            atomicAdd(&out[d], c);
            atomicAdd(&out[s], -c);
        }
    }
}

extern "C" void kernel_launch(void* const* d_in, const int* in_sizes, int n_in,
                              void* d_out, int out_size, void* d_ws, size_t ws_size,
                              hipStream_t stream) {
    // inputs: t(0), v(1), src(2), dst(3), theta_sd_1(4), theta_sd_2(5), conductance(6)
    const float* v    = (const float*)d_in[1];
    const int*   src  = (const int*)  d_in[2];
    const int*   dst  = (const int*)  d_in[3];
    const float* t1   = (const float*)d_in[4];
    const float* t2   = (const float*)d_in[5];
    const float* cond = (const float*)d_in[6];
    float* out = (float*)d_out;
    const int E = in_sizes[2];
    const int N = out_size;

    const size_t curBytes = (((size_t)E * sizeof(__half)) + 255) & ~(size_t)255;
    const size_t perCopy  = (size_t)N * sizeof(float);

    int B = 0;
    const int cands[] = {64, 48, 32, 16, 8};
    for (int c : cands) {
        if (curBytes + (size_t)c * perCopy <= ws_size) { B = c; break; }
    }

    if (B > 0) {
        __half* cur    = (__half*)d_ws;
        float* partial = (float*)((char*)d_ws + curBytes);

        int chunks8 = (E + 7) / 8;
        int g0 = (chunks8 + P0_BLK - 1) / P0_BLK;
        if (g0 > 2048) g0 = 2048;
        if (g0 < 1) g0 = 1;
        edge_current_kernel<<<g0, P0_BLK, 0, stream>>>(v, src, dst, t1, t2, cond, cur, E);

        const int R = (N + RANGE - 1) / RANGE;
        const int E4 = E & ~3;
        int sliceLen = (((E4 + B - 1) / B) + 3) & ~3;
        range_accum_kernel<<<R * B, P1_BLK, 0, stream>>>(src, dst, cur, partial,
                                                         N, E, B, R, sliceLen);

        if ((N & 3) == 0) {
            int n4 = N / 4;
            reduce_kernel<<<(n4 + 255) / 256, 256, 0, stream>>>(partial, out, n4, B);
        } else {
            reduce_scalar_kernel<<<(N + 255) / 256, 256, 0, stream>>>(partial, out, N, B);
        }
    } else {
        hipMemsetAsync(out, 0, perCopy, stream);
        int grid = (E + 255) / 256;
        if (grid > 2048) grid = 2048;
        atomic_fallback_kernel<<<grid, 256, 0, stream>>>(v, src, dst, t1, t2, cond, out, E);
    }
}